// Round 4
// baseline (161.721 us; speedup 1.0000x reference)
//
#include <hip/hip_runtime.h>

#define EPS_F 1e-6f
#define BLK   256
#define WPB   4      // waves per block
#define GRID  2048   // 8 blocks/CU * 256 CU

// ---- Kernel 1: w = sigmoid(w_raw), 19x19 = 361 floats into d_ws ----
__global__ void sigmoid_w_kernel(const float* __restrict__ w_raw,
                                 float* __restrict__ w) {
    int i = threadIdx.x;
    if (i < 361) {
        w[i] = 1.0f / (1.0f + expf(-w_raw[i]));
    }
}

__device__ __forceinline__ float mixf(float a, float b, float wv) {
    float mn = fminf(a, b);
    float mx = fmaxf(a, b);
    return fmaf(wv, mn - mx, mx);   // w*mn + (1-w)*mx
}

// ---- Kernel 2: wave-autonomous, barrier-free, grid-stride ----
// Each wave owns a private 64-sample LDS slab (4864 B). No __syncthreads():
// a wave's LDS ops complete in order, so ds_write -> waitcnt(lgkm 0) ->
// ds_read cross-lane within the wave is safe. Waves drift out of phase,
// overlapping one wave's store burst with another's compute.
__global__ __launch_bounds__(BLK, 8) void tree_forward_kernel(
    const float* __restrict__ c20,   // (B, 20)
    const float* __restrict__ w,     // (19, 19) sigmoid'd
    float* __restrict__ out,         // (B, 19)
    int B)
{
    __shared__ float so[WPB][64 * 19];   // 4 x 4864 B = 19456 B -> 8 blocks/CU

    const int lane = threadIdx.x & 63;
    const int wid  = threadIdx.x >> 6;
    float* __restrict__ slab = so[wid];

    const long long nSlab  = ((long long)B + 63) >> 6;       // 64-sample slabs
    const long long stride = (long long)gridDim.x * WPB;

    for (long long sl = (long long)blockIdx.x * WPB + wid; sl < nSlab; sl += stride) {
        const long long s = sl * 64 + lane;

        float x[20];
        if (s < B) {
            const float4* p = reinterpret_cast<const float4*>(c20 + s * 20);
            #pragma unroll
            for (int q = 0; q < 5; ++q) {
                float4 v = p[q];
                x[4*q+0] = v.x; x[4*q+1] = v.y; x[4*q+2] = v.z; x[4*q+3] = v.w;
            }
        } else {
            #pragma unroll
            for (int i = 0; i < 20; ++i) x[i] = 0.0f;
        }

        // Layer-0 min/max pairs are tree-independent: compute once (30 ops),
        // then layer 0 per tree is just 10 FMAs. y[k] = w*mn+(1-w)*mx
        //                                            = fma(w, mn-mx, mx).
        float mx[10], d[10];
        #pragma unroll
        for (int k = 0; k < 10; ++k) {
            float a = x[2*k], b = x[2*k+1];
            float mn = fminf(a, b);
            mx[k] = fmaxf(a, b);
            d[k]  = mn - mx[k];
        }

        #pragma unroll
        for (int t = 0; t < 19; ++t) {
            const float* wr = w + t * 19;

            // layer 0: 20 -> 10  (10 FMAs, shared min/max)
            float y[10];
            #pragma unroll
            for (int k = 0; k < 10; ++k)
                y[k] = fmaf(wr[k], d[k], mx[k]);

            // layer 1: 10 -> 5
            float z[5];
            #pragma unroll
            for (int k = 0; k < 5; ++k)
                z[k] = mixf(y[2*k], y[2*k+1], wr[10 + k]);

            // layer 2: 5 -> 2 + carry z[4]
            float u0 = mixf(z[0], z[1], wr[15]);
            float u1 = mixf(z[2], z[3], wr[16]);

            // layer 3: 3 -> 1 + carry
            float v0 = mixf(u0, u1, wr[17]);

            // layer 4: 2 -> 1
            float r = mixf(v0, z[4], wr[18]);

            slab[lane * 19 + t] = fminf(fmaxf(r, EPS_F), 1.0f - EPS_F);
        }

        // Wave-internal transpose handoff: wait own wave's DS writes, keep
        // compiler from reordering, then read cross-lane. No block barrier.
        __builtin_amdgcn_s_waitcnt(0xC07F);     // lgkmcnt(0), vm/exp = no-wait
        __builtin_amdgcn_wave_barrier();

        const long long slabBase = sl * 1216;   // dword offset into out
        if (sl * 64 + 64 <= (long long)B) {
            // full slab: 1216 dwords = 304 float4, coalesced
            const float4* ls = reinterpret_cast<const float4*>(slab);
            float4* gd = reinterpret_cast<float4*>(out + slabBase);
            #pragma unroll
            for (int i = 0; i < 5; ++i) {
                int idx = lane + i * 64;
                if (idx < 304) gd[idx] = ls[idx];
            }
        } else {
            const long long nDw = (long long)B * 19;
            for (int i = lane; i < 1216; i += 64) {
                long long g = slabBase + i;
                if (g < nDw) out[g] = slab[i];
            }
        }
    }
}

extern "C" void kernel_launch(void* const* d_in, const int* in_sizes, int n_in,
                              void* d_out, int out_size, void* d_ws, size_t ws_size,
                              hipStream_t stream) {
    // setup_inputs order: p1 (B,) int, p2 (B,) int, c20 (B,20) f32, w_raw (19,19) f32
    const float* c20   = (const float*)d_in[2];
    const float* w_raw = (const float*)d_in[3];
    float* out = (float*)d_out;
    float* w   = (float*)d_ws;   // 361 floats of scratch

    int B = in_sizes[0];

    sigmoid_w_kernel<<<1, 384, 0, stream>>>(w_raw, w);

    long long nSlab = ((long long)B + 63) >> 6;
    int grid = (int)((nSlab + WPB - 1) / WPB);
    if (grid > GRID) grid = GRID;
    tree_forward_kernel<<<grid, BLK, 0, stream>>>(c20, w, out, B);
}

// Round 5
// 154.238 us; speedup vs baseline: 1.0485x; 1.0485x over previous
//
#include <hip/hip_runtime.h>

#define EPS_F 1e-6f
#define BLK   256

// ---- Kernel 1: w = sigmoid(w_raw), 19x19 = 361 floats into d_ws ----
__global__ void sigmoid_w_kernel(const float* __restrict__ w_raw,
                                 float* __restrict__ w) {
    int i = threadIdx.x;
    if (i < 361) {
        w[i] = 1.0f / (1.0f + expf(-w_raw[i]));
    }
}

__device__ __forceinline__ float mixf(float a, float b, float wv) {
    float mn = fminf(a, b);
    float mx = fmaxf(a, b);
    return fmaf(wv, mn - mx, mx);   // w*mn + (1-w)*mx
}

__device__ __forceinline__ float clampf(float r) {
    return fminf(fmaxf(r, EPS_F), 1.0f - EPS_F);
}

// ---- Kernel 2: 1 sample/thread, trees in PAIRS for ILP, LDS copy-out ----
__global__ __launch_bounds__(BLK) void tree_forward_kernel(
    const float* __restrict__ c20,   // (B, 20)
    const float* __restrict__ w,     // (19, 19) sigmoid'd
    float* __restrict__ out,         // (B, 19)
    int B)
{
    __shared__ float so[BLK * 19];   // 19456 B -> 8 blocks/CU cap

    const int tid = threadIdx.x;
    const long long S0 = (long long)blockIdx.x * BLK;
    const long long s  = S0 + tid;

    float x[20];
    if (s < B) {
        const float4* p = reinterpret_cast<const float4*>(c20 + s * 20);
        #pragma unroll
        for (int q = 0; q < 5; ++q) {
            float4 v = p[q];
            x[4*q+0] = v.x; x[4*q+1] = v.y; x[4*q+2] = v.z; x[4*q+3] = v.w;
        }
    } else {
        #pragma unroll
        for (int i = 0; i < 20; ++i) x[i] = 0.0f;
    }

    // Layer-0 min/max pairs are tree-independent: compute once (30 ops),
    // then layer 0 per tree is just 10 FMAs: y = fma(w, mn-mx, mx).
    float mx[10], d[10];
    #pragma unroll
    for (int k = 0; k < 10; ++k) {
        float a = x[2*k], b = x[2*k+1];
        float mn = fminf(a, b);
        mx[k] = fmaxf(a, b);
        d[k]  = mn - mx[k];
    }

    float* __restrict__ o = &so[tid * 19];

    // Two independent trees per iteration: 2 interleaved dependency chains,
    // weight s_loads for the pair overlap the previous pair's compute.
    #pragma unroll
    for (int tp = 0; tp < 9; ++tp) {
        const int t0 = 2 * tp, t1 = 2 * tp + 1;
        const float* wr0 = w + t0 * 19;
        const float* wr1 = w + t1 * 19;

        float y0[10], y1[10];
        #pragma unroll
        for (int k = 0; k < 10; ++k) {
            y0[k] = fmaf(wr0[k], d[k], mx[k]);
            y1[k] = fmaf(wr1[k], d[k], mx[k]);
        }

        float z0[5], z1[5];
        #pragma unroll
        for (int k = 0; k < 5; ++k) {
            z0[k] = mixf(y0[2*k], y0[2*k+1], wr0[10 + k]);
            z1[k] = mixf(y1[2*k], y1[2*k+1], wr1[10 + k]);
        }

        float u00 = mixf(z0[0], z0[1], wr0[15]);
        float u01 = mixf(z0[2], z0[3], wr0[16]);
        float u10 = mixf(z1[0], z1[1], wr1[15]);
        float u11 = mixf(z1[2], z1[3], wr1[16]);

        float v0 = mixf(u00, u01, wr0[17]);
        float v1 = mixf(u10, u11, wr1[17]);

        float r0 = mixf(v0, z0[4], wr0[18]);
        float r1 = mixf(v1, z1[4], wr1[18]);

        o[t0] = clampf(r0);
        o[t1] = clampf(r1);
    }

    // tree 18 (last, unpaired)
    {
        const float* wr = w + 18 * 19;
        float y[10];
        #pragma unroll
        for (int k = 0; k < 10; ++k)
            y[k] = fmaf(wr[k], d[k], mx[k]);
        float z[5];
        #pragma unroll
        for (int k = 0; k < 5; ++k)
            z[k] = mixf(y[2*k], y[2*k+1], wr[10 + k]);
        float u0 = mixf(z[0], z[1], wr[15]);
        float u1 = mixf(z[2], z[3], wr[16]);
        float v0 = mixf(u0, u1, wr[17]);
        float r  = mixf(v0, z[4], wr[18]);
        o[18] = clampf(r);
    }

    __syncthreads();

    // Cooperative coalesced copy-out: BLK*19 = 4864 dwords = 1216 float4.
    const long long nDw    = (long long)B * 19;
    const long long baseDw = S0 * 19;            // 4864/block -> divisible by 4
    const float4* ls = reinterpret_cast<const float4*>(so);

    #pragma unroll
    for (int i = tid; i < (BLK * 19) / 4; i += BLK) {
        long long g = baseDw + (long long)i * 4;
        if (g + 3 < nDw) {
            *reinterpret_cast<float4*>(out + g) = ls[i];
        } else if (g < nDw) {
            float4 v = ls[i];
            out[g] = v.x;
            if (g + 1 < nDw) out[g + 1] = v.y;
            if (g + 2 < nDw) out[g + 2] = v.z;
        }
    }
}

extern "C" void kernel_launch(void* const* d_in, const int* in_sizes, int n_in,
                              void* d_out, int out_size, void* d_ws, size_t ws_size,
                              hipStream_t stream) {
    // setup_inputs order: p1 (B,) int, p2 (B,) int, c20 (B,20) f32, w_raw (19,19) f32
    const float* c20   = (const float*)d_in[2];
    const float* w_raw = (const float*)d_in[3];
    float* out = (float*)d_out;
    float* w   = (float*)d_ws;   // 361 floats of scratch

    int B = in_sizes[0];

    sigmoid_w_kernel<<<1, 384, 0, stream>>>(w_raw, w);

    int grid = (B + BLK - 1) / BLK;
    tree_forward_kernel<<<grid, BLK, 0, stream>>>(c20, w, out, B);
}